// Round 1
// baseline (644.545 us; speedup 1.0000x reference)
//
#include <hip/hip_runtime.h>
#include <hip/hip_bf16.h>

// Problem constants (fixed by reference file)
#define N_NODES 50000
#define N_EDGES 800000
#define DIM 128

// ---------------------------------------------------------------------------
// zero ints
__global__ void zero_ints(int* __restrict__ p, int n) {
    int i = blockIdx.x * blockDim.x + threadIdx.x;
    if (i < n) p[i] = 0;
}

// histogram of dst
__global__ void hist_kernel(const int* __restrict__ dst, int* __restrict__ counts, int e) {
    int i = blockIdx.x * blockDim.x + threadIdx.x;
    if (i < e) atomicAdd(&counts[dst[i]], 1);
}

// single-block exclusive scan: row_start[0]=0, row_start[i+1]=sum(counts[0..i])
__global__ void scan_kernel(const int* __restrict__ counts, int* __restrict__ row_start, int n) {
    __shared__ int sdata[1024];
    __shared__ int s_carry;
    const int tid = threadIdx.x;
    if (tid == 0) { s_carry = 0; row_start[0] = 0; }
    __syncthreads();
    for (int base = 0; base < n; base += 4096) {
        int i0 = base + tid * 4;
        int a0 = (i0 + 0 < n) ? counts[i0 + 0] : 0;
        int a1 = (i0 + 1 < n) ? counts[i0 + 1] : 0;
        int a2 = (i0 + 2 < n) ? counts[i0 + 2] : 0;
        int a3 = (i0 + 3 < n) ? counts[i0 + 3] : 0;
        int s1 = a0 + a1, s2 = s1 + a2, s3 = s2 + a3;
        int carry = s_carry;
        sdata[tid] = s3;
        __syncthreads();
        int acc = s3;
        for (int off = 1; off < 1024; off <<= 1) {
            int t = (tid >= off) ? sdata[tid - off] : 0;
            __syncthreads();
            acc += t;
            sdata[tid] = acc;
            __syncthreads();
        }
        int excl = carry + acc - s3;
        if (i0 + 0 < n) row_start[i0 + 1] = excl + a0;
        if (i0 + 1 < n) row_start[i0 + 2] = excl + s1;
        if (i0 + 2 < n) row_start[i0 + 3] = excl + s2;
        if (i0 + 3 < n) row_start[i0 + 4] = excl + s3;
        int total = sdata[1023];
        __syncthreads();
        if (tid == 0) s_carry = carry + total;
        __syncthreads();
    }
}

// scatter edges into CSR order (perm arrays hold src id + weight, dst-sorted)
__global__ void fill_kernel(const int* __restrict__ src, const int* __restrict__ dst,
                            const float* __restrict__ ew, const int* __restrict__ row_start,
                            int* __restrict__ cursor, int* __restrict__ permS,
                            float* __restrict__ permW, int e) {
    int i = blockIdx.x * blockDim.x + threadIdx.x;
    if (i < e) {
        int d = dst[i];
        int pos = row_start[d] + atomicAdd(&cursor[d], 1);
        permS[pos] = src[i];
        permW[pos] = ew[i];
    }
}

// pack [w_rel; w_root] -> Wc[layer][256][128]
__global__ void pack_w(const float* __restrict__ wr0, const float* __restrict__ wt0,
                       const float* __restrict__ wr1, const float* __restrict__ wt1,
                       const float* __restrict__ wr2, const float* __restrict__ wt2,
                       float* __restrict__ Wc) {
    int id = blockIdx.x * blockDim.x + threadIdx.x;
    if (id >= 3 * 256 * 128) return;
    int layer = id >> 15;
    int rem = id & 32767;
    int k = rem >> 7, j = rem & 127;
    const float* wr = (layer == 0) ? wr0 : (layer == 1) ? wr1 : wr2;
    const float* wt = (layer == 0) ? wt0 : (layer == 1) ? wt1 : wt2;
    Wc[id] = (k < 128) ? wr[k * 128 + j] : wt[(k - 128) * 128 + j];
}

// gather aggregation: one wave (64 lanes) per node, 2 floats/lane
__global__ __launch_bounds__(256)
void aggregate_kernel(const float* __restrict__ h, const int* __restrict__ row_start,
                      const int* __restrict__ permS, const float* __restrict__ permW,
                      float* __restrict__ agg, int n) {
    int gwave = (blockIdx.x * 256 + threadIdx.x) >> 6;
    int lane = threadIdx.x & 63;
    if (gwave >= n) return;
    int beg = row_start[gwave];
    int end = row_start[gwave + 1];
    float accx = 0.f, accy = 0.f;
    for (int e = beg; e < end; e += 64) {
        int cnt = end - e;
        if (cnt > 64) cnt = 64;
        int sv = 0; float wv = 0.f;
        if (lane < cnt) { sv = permS[e + lane]; wv = permW[e + lane]; }
        for (int j = 0; j < cnt; ++j) {
            int s = __shfl(sv, j, 64);
            float w = __shfl(wv, j, 64);
            float2 v = ((const float2*)(h + (size_t)s * DIM))[lane];
            accx += w * v.x;
            accy += w * v.y;
        }
    }
    float2 r; r.x = accx; r.y = accy;
    ((float2*)(agg + (size_t)gwave * DIM))[lane] = r;
}

// fp32 SGEMM: C[n,128] = [Aagg | Ah] (n x 256) @ W (256 x 128) + bias, optional relu
// BM=64 BN=128 BK=32, 256 threads, 4x8 microtile
#define BM 64
#define BN 128
#define BK 32
__global__ __launch_bounds__(256)
void gemm_kernel(const float* __restrict__ Aagg, const float* __restrict__ Ah,
                 const float* __restrict__ W, const float* __restrict__ bias,
                 float* __restrict__ C, int n, int relu) {
    __shared__ float As[BK][BM + 4];
    __shared__ float Ws[BK][BN];
    const int tid = threadIdx.x;
    const int tx = tid & 15;   // col group (8 cols each)
    const int ty = tid >> 4;   // row group (4 rows each)
    const int row0 = blockIdx.x * BM;

    float acc[4][8];
#pragma unroll
    for (int i = 0; i < 4; ++i)
#pragma unroll
        for (int j = 0; j < 8; ++j) acc[i][j] = 0.f;

    for (int k0 = 0; k0 < 256; k0 += BK) {
        const float* Aptr = (k0 < 128) ? Aagg : Ah;
        const int kk = (k0 < 128) ? k0 : (k0 - 128);
        // A tile: 64 rows x 32 k  (2048 elems = 8 per thread)
#pragma unroll
        for (int t = 0; t < 8; ++t) {
            int idx = tid + t * 256;
            int m = idx >> 5, k = idx & 31;
            int r = row0 + m;
            As[k][m] = (r < n) ? Aptr[(size_t)r * DIM + kk + k] : 0.f;
        }
        // W tile: 32 k x 128 j (4096 elems = 16 per thread)
#pragma unroll
        for (int t = 0; t < 16; ++t) {
            int idx = tid + t * 256;
            int k = idx >> 7, j = idx & 127;
            Ws[k][j] = W[(size_t)(k0 + k) * BN + j];
        }
        __syncthreads();
#pragma unroll
        for (int k = 0; k < BK; ++k) {
            float a[4], w[8];
#pragma unroll
            for (int i = 0; i < 4; ++i) a[i] = As[k][ty * 4 + i];
#pragma unroll
            for (int j = 0; j < 8; ++j) w[j] = Ws[k][tx * 8 + j];
#pragma unroll
            for (int i = 0; i < 4; ++i)
#pragma unroll
                for (int j = 0; j < 8; ++j) acc[i][j] += a[i] * w[j];
        }
        __syncthreads();
    }
#pragma unroll
    for (int i = 0; i < 4; ++i) {
        int r = row0 + ty * 4 + i;
        if (r < n) {
#pragma unroll
            for (int j = 0; j < 8; ++j) {
                float v = acc[i][j] + bias[tx * 8 + j];
                if (relu) v = fmaxf(v, 0.f);
                C[(size_t)r * DIM + tx * 8 + j] = v;
            }
        }
    }
}

extern "C" void kernel_launch(void* const* d_in, const int* in_sizes, int n_in,
                              void* d_out, int out_size, void* d_ws, size_t ws_size,
                              hipStream_t stream) {
    const int N = N_NODES, E = N_EDGES;

    const float* x   = (const float*)d_in[0];
    const int*   ei  = (const int*)d_in[1];
    const float* ea  = (const float*)d_in[2];
    const float* wr0 = (const float*)d_in[3];
    const float* br0 = (const float*)d_in[4];
    const float* wt0 = (const float*)d_in[5];
    const float* wr1 = (const float*)d_in[6];
    const float* br1 = (const float*)d_in[7];
    const float* wt1 = (const float*)d_in[8];
    const float* wr2 = (const float*)d_in[9];
    const float* br2 = (const float*)d_in[10];
    const float* wt2 = (const float*)d_in[11];
    const int* srcI = ei;      // edge_index[0]
    const int* dstI = ei + E;  // edge_index[1]
    float* out = (float*)d_out;

    // workspace layout
    float* bufA  = (float*)d_ws;                       // N*128 f32
    float* bufB  = bufA + (size_t)N * DIM;             // N*128 f32
    float* Wc    = bufB + (size_t)N * DIM;             // 3*256*128 f32
    float* permW = Wc + 3 * 256 * 128;                 // E f32
    int*   permS = (int*)(permW + E);                  // E i32
    int*   rowst = permS + E;                          // N+1 i32
    int*   cursor = rowst + (N + 1);                   // N i32
    int*   counts = cursor + N;                        // N i32

    // CSR build (per launch — identical work every call)
    zero_ints<<<(3 * N + 1 + 255) / 256, 256, 0, stream>>>(rowst, 3 * N + 1);
    hist_kernel<<<(E + 255) / 256, 256, 0, stream>>>(dstI, counts, E);
    scan_kernel<<<1, 1024, 0, stream>>>(counts, rowst, N);
    fill_kernel<<<(E + 255) / 256, 256, 0, stream>>>(srcI, dstI, ea, rowst, cursor, permS, permW, E);
    pack_w<<<(3 * 32768 + 255) / 256, 256, 0, stream>>>(wr0, wt0, wr1, wt1, wr2, wt2, Wc);

    const int aggGrid  = (N + 3) / 4;       // 4 waves/block, 1 wave/node
    const int gemmGrid = (N + BM - 1) / BM;

    // layer 0: h0 = x
    aggregate_kernel<<<aggGrid, 256, 0, stream>>>(x, rowst, permS, permW, bufB, N);
    gemm_kernel<<<gemmGrid, 256, 0, stream>>>(bufB, x, Wc, br0, bufA, N, 1);
    // layer 1: h1 = bufA ; gemm writes in-place over agg (bufB) — safe (row-local)
    aggregate_kernel<<<aggGrid, 256, 0, stream>>>(bufA, rowst, permS, permW, bufB, N);
    gemm_kernel<<<gemmGrid, 256, 0, stream>>>(bufB, bufA, Wc + 32768, br1, bufB, N, 1);
    // layer 2: h2 = bufB
    aggregate_kernel<<<aggGrid, 256, 0, stream>>>(bufB, rowst, permS, permW, bufA, N);
    gemm_kernel<<<gemmGrid, 256, 0, stream>>>(bufA, bufB, Wc + 65536, br2, out, N, 0);
}

// Round 2
// 461.217 us; speedup vs baseline: 1.3975x; 1.3975x over previous
//
#include <hip/hip_runtime.h>
#include <hip/hip_bf16.h>

#define N_NODES 50000
#define N_EDGES 800000
#define DIM 128

typedef float floatx4 __attribute__((ext_vector_type(4)));
typedef short shortx8 __attribute__((ext_vector_type(8)));

__device__ __forceinline__ unsigned short f2bf(float f) {
    union { float f; unsigned int u; } c; c.f = f;
    unsigned int u = c.u;
    unsigned int r = (u + 0x7FFFu + ((u >> 16) & 1u)) >> 16;
    return (unsigned short)r;
}
__device__ __forceinline__ float bf2f(unsigned short h) {
    union { unsigned int u; float f; } c; c.u = ((unsigned int)h) << 16;
    return c.f;
}

// ---------------------------------------------------------------------------
__global__ void zero_ints(int* __restrict__ p, int n) {
    int i = blockIdx.x * blockDim.x + threadIdx.x;
    if (i < n) p[i] = 0;
}

__global__ void hist_kernel(const int* __restrict__ dst, int* __restrict__ counts, int e) {
    int i = blockIdx.x * blockDim.x + threadIdx.x;
    if (i < e) atomicAdd(&counts[dst[i]], 1);
}

// single-block exclusive scan: row_start[0]=0, row_start[i+1]=sum(counts[0..i])
__global__ void scan_kernel(const int* __restrict__ counts, int* __restrict__ row_start, int n) {
    __shared__ int sdata[1024];
    __shared__ int s_carry;
    const int tid = threadIdx.x;
    if (tid == 0) { s_carry = 0; row_start[0] = 0; }
    __syncthreads();
    for (int base = 0; base < n; base += 4096) {
        int i0 = base + tid * 4;
        int a0 = (i0 + 0 < n) ? counts[i0 + 0] : 0;
        int a1 = (i0 + 1 < n) ? counts[i0 + 1] : 0;
        int a2 = (i0 + 2 < n) ? counts[i0 + 2] : 0;
        int a3 = (i0 + 3 < n) ? counts[i0 + 3] : 0;
        int s1 = a0 + a1, s2 = s1 + a2, s3 = s2 + a3;
        int carry = s_carry;
        sdata[tid] = s3;
        __syncthreads();
        int acc = s3;
        for (int off = 1; off < 1024; off <<= 1) {
            int t = (tid >= off) ? sdata[tid - off] : 0;
            __syncthreads();
            acc += t;
            sdata[tid] = acc;
            __syncthreads();
        }
        int excl = carry + acc - s3;
        if (i0 + 0 < n) row_start[i0 + 1] = excl + a0;
        if (i0 + 1 < n) row_start[i0 + 2] = excl + s1;
        if (i0 + 2 < n) row_start[i0 + 3] = excl + s2;
        if (i0 + 3 < n) row_start[i0 + 4] = excl + s3;
        int total = sdata[1023];
        __syncthreads();
        if (tid == 0) s_carry = carry + total;
        __syncthreads();
    }
}

__global__ void fill_kernel(const int* __restrict__ src, const int* __restrict__ dst,
                            const float* __restrict__ ew, const int* __restrict__ row_start,
                            int* __restrict__ cursor, int* __restrict__ permS,
                            float* __restrict__ permW, int e) {
    int i = blockIdx.x * blockDim.x + threadIdx.x;
    if (i < e) {
        int d = dst[i];
        int pos = row_start[d] + atomicAdd(&cursor[d], 1);
        permS[pos] = src[i];
        permW[pos] = ew[i];
    }
}

// pack [w_rel; w_root] (fp32) -> bf16 MFMA B-fragment layout
// Wp index = ((layer*8 + t)*8 + ct)*64*8 + L*8 + j
//   element = W[k][c], k = t*32 + (L>>4)*8 + j, c = ct*16 + (L&15)
__global__ void pack_w_bf16(const float* __restrict__ wr0, const float* __restrict__ wt0,
                            const float* __restrict__ wr1, const float* __restrict__ wt1,
                            const float* __restrict__ wr2, const float* __restrict__ wt2,
                            unsigned short* __restrict__ Wp) {
    int id = blockIdx.x * blockDim.x + threadIdx.x;
    if (id >= 3 * 32768) return;
    int layer = id >> 15;
    int rem = id & 32767;
    int j  = rem & 7;
    int L  = (rem >> 3) & 63;
    int ct = (rem >> 9) & 7;
    int t  = rem >> 12;
    int k = t * 32 + (L >> 4) * 8 + j;
    int c = ct * 16 + (L & 15);
    const float* wr = (layer == 0) ? wr0 : (layer == 1) ? wr1 : wr2;
    const float* wt = (layer == 0) ? wt0 : (layer == 1) ? wt1 : wt2;
    float v = (k < 128) ? wr[k * 128 + c] : wt[(k - 128) * 128 + c];
    Wp[id] = f2bf(v);
}

__global__ void cvt_f2b(const float* __restrict__ x, unsigned short* __restrict__ xb, int n) {
    int i = blockIdx.x * blockDim.x + threadIdx.x;
    if (i < n) xb[i] = f2bf(x[i]);
}

// gather aggregation over bf16 h: one wave per node, 2 cols/lane (bf16x2 = 4B load)
__global__ __launch_bounds__(256)
void aggregate_bf16(const unsigned short* __restrict__ h, const int* __restrict__ row_start,
                    const int* __restrict__ permS, const float* __restrict__ permW,
                    unsigned short* __restrict__ agg, int n) {
    int gwave = (blockIdx.x * 256 + threadIdx.x) >> 6;
    int lane = threadIdx.x & 63;
    if (gwave >= n) return;
    int beg = row_start[gwave];
    int end = row_start[gwave + 1];
    float accx = 0.f, accy = 0.f;
    for (int e = beg; e < end; e += 64) {
        int cnt = end - e;
        if (cnt > 64) cnt = 64;
        int sv = 0; float wv = 0.f;
        if (lane < cnt) { sv = permS[e + lane]; wv = permW[e + lane]; }
        for (int j = 0; j < cnt; ++j) {
            int s = __shfl(sv, j, 64);
            float w = __shfl(wv, j, 64);
            unsigned int p = ((const unsigned int*)(h + (size_t)s * DIM))[lane];
            accx += w * bf2f((unsigned short)(p & 0xFFFF));
            accy += w * bf2f((unsigned short)(p >> 16));
        }
    }
    unsigned int r = (unsigned int)f2bf(accx) | ((unsigned int)f2bf(accy) << 16);
    ((unsigned int*)(agg + (size_t)gwave * DIM))[lane] = r;
}

// MFMA GEMM: C[n,128] = [G | H] (n x 256, bf16) @ W (256x128, bf16 pre-packed) + bias
// block = 256 thr (4 waves), wave owns 32 rows x 128 cols -> block = 128 rows.
// A-frag: lane L holds A[row0 + (L&15)][t*32 + (L>>4)*8 + j], j=0..7 -> 16B contig load.
// C/D:    lane L holds D[(L>>4)*4 + i][L&15].
__global__ __launch_bounds__(256)
void gemm_mfma(const unsigned short* __restrict__ G, const unsigned short* __restrict__ H,
               const unsigned short* __restrict__ Wp, const float* __restrict__ bias,
               float* __restrict__ outF, unsigned short* __restrict__ outB,
               int n, int relu) {
    const int L   = threadIdx.x & 63;
    const int wid = threadIdx.x >> 6;
    const int m = L & 15, q = L >> 4;
    const int rowT = blockIdx.x * 128 + wid * 32;
    int r0 = rowT + m;
    int r1 = rowT + 16 + m;
    int rr0 = (r0 < n) ? r0 : (n - 1);
    int rr1 = (r1 < n) ? r1 : (n - 1);
    const int ko = q * 8;

    floatx4 acc[2][8];
#pragma unroll
    for (int mi = 0; mi < 2; ++mi)
#pragma unroll
        for (int ct = 0; ct < 8; ++ct) acc[mi][ct] = (floatx4){0.f, 0.f, 0.f, 0.f};

#pragma unroll
    for (int t = 0; t < 8; ++t) {
        const unsigned short* A = (t < 4) ? G : H;
        const int kk = (t & 3) * 32 + ko;
        shortx8 a0 = *(const shortx8*)(A + (size_t)rr0 * DIM + kk);
        shortx8 a1 = *(const shortx8*)(A + (size_t)rr1 * DIM + kk);
        const unsigned short* wp = Wp + (size_t)t * 4096 + L * 8;
#pragma unroll
        for (int ct = 0; ct < 8; ++ct) {
            shortx8 b = *(const shortx8*)(wp + ct * 512);
            acc[0][ct] = __builtin_amdgcn_mfma_f32_16x16x32_bf16(a0, b, acc[0][ct], 0, 0, 0);
            acc[1][ct] = __builtin_amdgcn_mfma_f32_16x16x32_bf16(a1, b, acc[1][ct], 0, 0, 0);
        }
    }

#pragma unroll
    for (int ct = 0; ct < 8; ++ct) {
        int col = ct * 16 + m;
        float bv = bias[col];
#pragma unroll
        for (int mi = 0; mi < 2; ++mi) {
#pragma unroll
            for (int i = 0; i < 4; ++i) {
                int row = rowT + mi * 16 + q * 4 + i;
                if (row < n) {
                    float v = acc[mi][ct][i] + bv;
                    if (relu) v = fmaxf(v, 0.f);
                    if (outF) outF[(size_t)row * DIM + col] = v;
                    else      outB[(size_t)row * DIM + col] = f2bf(v);
                }
            }
        }
    }
}

extern "C" void kernel_launch(void* const* d_in, const int* in_sizes, int n_in,
                              void* d_out, int out_size, void* d_ws, size_t ws_size,
                              hipStream_t stream) {
    const int N = N_NODES, E = N_EDGES;

    const float* x   = (const float*)d_in[0];
    const int*   ei  = (const int*)d_in[1];
    const float* ea  = (const float*)d_in[2];
    const float* wr0 = (const float*)d_in[3];
    const float* br0 = (const float*)d_in[4];
    const float* wt0 = (const float*)d_in[5];
    const float* wr1 = (const float*)d_in[6];
    const float* br1 = (const float*)d_in[7];
    const float* wt1 = (const float*)d_in[8];
    const float* wr2 = (const float*)d_in[9];
    const float* br2 = (const float*)d_in[10];
    const float* wt2 = (const float*)d_in[11];
    const int* srcI = ei;
    const int* dstI = ei + E;
    float* out = (float*)d_out;

    // workspace layout (bf16 buffers)
    unsigned short* X  = (unsigned short*)d_ws;       // N*128 bf16
    unsigned short* H  = X + (size_t)N * DIM;         // N*128 bf16
    unsigned short* G  = H + (size_t)N * DIM;         // N*128 bf16
    unsigned short* Wp = G + (size_t)N * DIM;         // 3*32768 bf16
    float* permW = (float*)(Wp + 3 * 32768);          // E f32
    int*   permS = (int*)(permW + E);                 // E i32
    int*   rowst = permS + E;                         // N+1 i32
    int*   cursor = rowst + (N + 1);                  // N i32
    int*   counts = cursor + N;                       // N i32

    // CSR build
    zero_ints<<<(3 * N + 1 + 255) / 256, 256, 0, stream>>>(rowst, 3 * N + 1);
    hist_kernel<<<(E + 255) / 256, 256, 0, stream>>>(dstI, counts, E);
    scan_kernel<<<1, 1024, 0, stream>>>(counts, rowst, N);
    fill_kernel<<<(E + 255) / 256, 256, 0, stream>>>(srcI, dstI, ea, rowst, cursor, permS, permW, E);
    pack_w_bf16<<<(3 * 32768 + 255) / 256, 256, 0, stream>>>(wr0, wt0, wr1, wt1, wr2, wt2, Wp);
    cvt_f2b<<<((N * DIM) + 255) / 256, 256, 0, stream>>>(x, X, N * DIM);

    const int aggGrid  = (N + 3) / 4;            // 4 waves/block, 1 wave/node
    const int gemmGrid = (N + 127) / 128;        // 128 rows/block

    // layer 0
    aggregate_bf16<<<aggGrid, 256, 0, stream>>>(X, rowst, permS, permW, G, N);
    gemm_mfma<<<gemmGrid, 256, 0, stream>>>(G, X, Wp, br0, nullptr, H, N, 1);
    // layer 1 (in-place H: each block reads only the rows it writes)
    aggregate_bf16<<<aggGrid, 256, 0, stream>>>(H, rowst, permS, permW, G, N);
    gemm_mfma<<<gemmGrid, 256, 0, stream>>>(G, H, Wp + 32768, br1, nullptr, H, N, 1);
    // layer 2 -> fp32 out
    aggregate_bf16<<<aggGrid, 256, 0, stream>>>(H, rowst, permS, permW, G, N);
    gemm_mfma<<<gemmGrid, 256, 0, stream>>>(G, H, Wp + 65536, br2, out, nullptr, N, 0);
}

// Round 3
// 378.288 us; speedup vs baseline: 1.7039x; 1.2192x over previous
//
#include <hip/hip_runtime.h>
#include <hip/hip_bf16.h>

#define N_NODES 50000
#define N_EDGES 800000
#define DIM 128

typedef float floatx4 __attribute__((ext_vector_type(4)));
typedef short shortx8 __attribute__((ext_vector_type(8)));

__device__ __forceinline__ unsigned short f2bf(float f) {
    union { float f; unsigned int u; } c; c.f = f;
    unsigned int u = c.u;
    unsigned int r = (u + 0x7FFFu + ((u >> 16) & 1u)) >> 16;
    return (unsigned short)r;
}
__device__ __forceinline__ float bf2f(unsigned short h) {
    union { unsigned int u; float f; } c; c.u = ((unsigned int)h) << 16;
    return c.f;
}
__device__ __forceinline__ float bflo(unsigned int p) { 
    union { unsigned int u; float f; } c; c.u = p << 16; return c.f;
}
__device__ __forceinline__ float bfhi(unsigned int p) {
    union { unsigned int u; float f; } c; c.u = p & 0xFFFF0000u; return c.f;
}

// ---------------------------------------------------------------------------
__global__ void zero_ints(int* __restrict__ p, int n) {
    int i = blockIdx.x * blockDim.x + threadIdx.x;
    if (i < n) p[i] = 0;
}

__global__ void hist_kernel(const int* __restrict__ dst, int* __restrict__ counts, int e) {
    int i = blockIdx.x * blockDim.x + threadIdx.x;
    if (i < e) atomicAdd(&counts[dst[i]], 1);
}

// single-block exclusive scan: row_start[0]=0, row_start[i+1]=sum(counts[0..i])
__global__ void scan_kernel(const int* __restrict__ counts, int* __restrict__ row_start, int n) {
    __shared__ int sdata[1024];
    __shared__ int s_carry;
    const int tid = threadIdx.x;
    if (tid == 0) { s_carry = 0; row_start[0] = 0; }
    __syncthreads();
    for (int base = 0; base < n; base += 4096) {
        int i0 = base + tid * 4;
        int a0 = (i0 + 0 < n) ? counts[i0 + 0] : 0;
        int a1 = (i0 + 1 < n) ? counts[i0 + 1] : 0;
        int a2 = (i0 + 2 < n) ? counts[i0 + 2] : 0;
        int a3 = (i0 + 3 < n) ? counts[i0 + 3] : 0;
        int s1 = a0 + a1, s2 = s1 + a2, s3 = s2 + a3;
        int carry = s_carry;
        sdata[tid] = s3;
        __syncthreads();
        int acc = s3;
        for (int off = 1; off < 1024; off <<= 1) {
            int t = (tid >= off) ? sdata[tid - off] : 0;
            __syncthreads();
            acc += t;
            sdata[tid] = acc;
            __syncthreads();
        }
        int excl = carry + acc - s3;
        if (i0 + 0 < n) row_start[i0 + 1] = excl + a0;
        if (i0 + 1 < n) row_start[i0 + 2] = excl + s1;
        if (i0 + 2 < n) row_start[i0 + 3] = excl + s2;
        if (i0 + 3 < n) row_start[i0 + 4] = excl + s3;
        int total = sdata[1023];
        __syncthreads();
        if (tid == 0) s_carry = carry + total;
        __syncthreads();
    }
}

// scatter edges into CSR order; single 8B store per edge: {src, weight_bits}
__global__ void fill_kernel(const int* __restrict__ src, const int* __restrict__ dst,
                            const float* __restrict__ ew, const int* __restrict__ row_start,
                            int* __restrict__ cursor, int2* __restrict__ perm2, int e) {
    int i = blockIdx.x * blockDim.x + threadIdx.x;
    if (i < e) {
        int d = dst[i];
        int pos = row_start[d] + atomicAdd(&cursor[d], 1);
        perm2[pos] = make_int2(src[i], __float_as_int(ew[i]));
    }
}

// pack [w_rel; w_root] (fp32) -> bf16 MFMA B-fragment layout
// Wp index = ((layer*8 + t)*8 + ct)*64*8 + L*8 + j
//   element = W[k][c], k = t*32 + (L>>4)*8 + j, c = ct*16 + (L&15)
__global__ void pack_w_bf16(const float* __restrict__ wr0, const float* __restrict__ wt0,
                            const float* __restrict__ wr1, const float* __restrict__ wt1,
                            const float* __restrict__ wr2, const float* __restrict__ wt2,
                            unsigned short* __restrict__ Wp) {
    int id = blockIdx.x * blockDim.x + threadIdx.x;
    if (id >= 3 * 32768) return;
    int layer = id >> 15;
    int rem = id & 32767;
    int j  = rem & 7;
    int L  = (rem >> 3) & 63;
    int ct = (rem >> 9) & 7;
    int t  = rem >> 12;
    int k = t * 32 + (L >> 4) * 8 + j;
    int c = ct * 16 + (L & 15);
    const float* wr = (layer == 0) ? wr0 : (layer == 1) ? wr1 : wr2;
    const float* wt = (layer == 0) ? wt0 : (layer == 1) ? wt1 : wt2;
    float v = (k < 128) ? wr[k * 128 + c] : wt[(k - 128) * 128 + c];
    Wp[id] = f2bf(v);
}

__global__ void cvt_f2b(const float* __restrict__ x, unsigned short* __restrict__ xb, int n) {
    int i = blockIdx.x * blockDim.x + threadIdx.x;
    if (i < n) xb[i] = f2bf(x[i]);
}

// gather aggregation over bf16 h: one wave per node, 2 cols/lane (4B row-chunk/lane)
// inner loop unrolled x4 -> 4 independent gathers in flight per wave
__global__ __launch_bounds__(256)
void aggregate_bf16(const unsigned short* __restrict__ h, const int* __restrict__ row_start,
                    const int2* __restrict__ perm2,
                    unsigned short* __restrict__ agg, int n) {
    int gwave = (blockIdx.x * 256 + threadIdx.x) >> 6;
    int lane = threadIdx.x & 63;
    if (gwave >= n) return;
    int beg = row_start[gwave];
    int end = row_start[gwave + 1];
    float accx = 0.f, accy = 0.f;
    for (int e = beg; e < end; e += 64) {
        int cnt = end - e;
        if (cnt > 64) cnt = 64;
        int sv = 0, wvb = 0;
        if (lane < cnt) { int2 p = perm2[e + lane]; sv = p.x; wvb = p.y; }
        int j = 0;
        for (; j + 4 <= cnt; j += 4) {
            int s0 = __shfl(sv, j + 0, 64), s1 = __shfl(sv, j + 1, 64);
            int s2 = __shfl(sv, j + 2, 64), s3 = __shfl(sv, j + 3, 64);
            float w0 = __int_as_float(__shfl(wvb, j + 0, 64));
            float w1 = __int_as_float(__shfl(wvb, j + 1, 64));
            float w2 = __int_as_float(__shfl(wvb, j + 2, 64));
            float w3 = __int_as_float(__shfl(wvb, j + 3, 64));
            unsigned int v0 = ((const unsigned int*)(h + (size_t)s0 * DIM))[lane];
            unsigned int v1 = ((const unsigned int*)(h + (size_t)s1 * DIM))[lane];
            unsigned int v2 = ((const unsigned int*)(h + (size_t)s2 * DIM))[lane];
            unsigned int v3 = ((const unsigned int*)(h + (size_t)s3 * DIM))[lane];
            accx += w0 * bflo(v0); accy += w0 * bfhi(v0);
            accx += w1 * bflo(v1); accy += w1 * bfhi(v1);
            accx += w2 * bflo(v2); accy += w2 * bfhi(v2);
            accx += w3 * bflo(v3); accy += w3 * bfhi(v3);
        }
        for (; j < cnt; ++j) {
            int s = __shfl(sv, j, 64);
            float w = __int_as_float(__shfl(wvb, j, 64));
            unsigned int v = ((const unsigned int*)(h + (size_t)s * DIM))[lane];
            accx += w * bflo(v); accy += w * bfhi(v);
        }
    }
    unsigned int r = (unsigned int)f2bf(accx) | ((unsigned int)f2bf(accy) << 16);
    ((unsigned int*)(agg + (size_t)gwave * DIM))[lane] = r;
}

// MFMA GEMM: C[n,128] = [G | H] (n x 256, bf16) @ W (256x128, bf16 pre-packed) + bias
// block = 256 thr (4 waves), wave owns 32 rows x 128 cols -> block = 128 rows.
// A-frag: lane L holds A[row0 + (L&15)][t*32 + (L>>4)*8 + j], j=0..7 -> 16B contig load.
// C/D:    lane L holds D[(L>>4)*4 + i][L&15].
__global__ __launch_bounds__(256)
void gemm_mfma(const unsigned short* __restrict__ G, const unsigned short* __restrict__ H,
               const unsigned short* __restrict__ Wp, const float* __restrict__ bias,
               float* __restrict__ outF, unsigned short* __restrict__ outB,
               int n, int relu) {
    const int L   = threadIdx.x & 63;
    const int wid = threadIdx.x >> 6;
    const int m = L & 15, q = L >> 4;
    const int rowT = blockIdx.x * 128 + wid * 32;
    int r0 = rowT + m;
    int r1 = rowT + 16 + m;
    int rr0 = (r0 < n) ? r0 : (n - 1);
    int rr1 = (r1 < n) ? r1 : (n - 1);
    const int ko = q * 8;

    floatx4 acc[2][8];
#pragma unroll
    for (int mi = 0; mi < 2; ++mi)
#pragma unroll
        for (int ct = 0; ct < 8; ++ct) acc[mi][ct] = (floatx4){0.f, 0.f, 0.f, 0.f};

#pragma unroll
    for (int t = 0; t < 8; ++t) {
        const unsigned short* A = (t < 4) ? G : H;
        const int kk = (t & 3) * 32 + ko;
        shortx8 a0 = *(const shortx8*)(A + (size_t)rr0 * DIM + kk);
        shortx8 a1 = *(const shortx8*)(A + (size_t)rr1 * DIM + kk);
        const unsigned short* wp = Wp + (size_t)t * 4096 + L * 8;
#pragma unroll
        for (int ct = 0; ct < 8; ++ct) {
            shortx8 b = *(const shortx8*)(wp + ct * 512);
            acc[0][ct] = __builtin_amdgcn_mfma_f32_16x16x32_bf16(a0, b, acc[0][ct], 0, 0, 0);
            acc[1][ct] = __builtin_amdgcn_mfma_f32_16x16x32_bf16(a1, b, acc[1][ct], 0, 0, 0);
        }
    }

#pragma unroll
    for (int ct = 0; ct < 8; ++ct) {
        int col = ct * 16 + m;
        float bv = bias[col];
#pragma unroll
        for (int mi = 0; mi < 2; ++mi) {
#pragma unroll
            for (int i = 0; i < 4; ++i) {
                int row = rowT + mi * 16 + q * 4 + i;
                if (row < n) {
                    float v = acc[mi][ct][i] + bv;
                    if (relu) v = fmaxf(v, 0.f);
                    if (outF) outF[(size_t)row * DIM + col] = v;
                    else      outB[(size_t)row * DIM + col] = f2bf(v);
                }
            }
        }
    }
}

extern "C" void kernel_launch(void* const* d_in, const int* in_sizes, int n_in,
                              void* d_out, int out_size, void* d_ws, size_t ws_size,
                              hipStream_t stream) {
    const int N = N_NODES, E = N_EDGES;

    const float* x   = (const float*)d_in[0];
    const int*   ei  = (const int*)d_in[1];
    const float* ea  = (const float*)d_in[2];
    const float* wr0 = (const float*)d_in[3];
    const float* br0 = (const float*)d_in[4];
    const float* wt0 = (const float*)d_in[5];
    const float* wr1 = (const float*)d_in[6];
    const float* br1 = (const float*)d_in[7];
    const float* wt1 = (const float*)d_in[8];
    const float* wr2 = (const float*)d_in[9];
    const float* br2 = (const float*)d_in[10];
    const float* wt2 = (const float*)d_in[11];
    const int* srcI = ei;
    const int* dstI = ei + E;
    float* out = (float*)d_out;

    // workspace layout
    unsigned short* X  = (unsigned short*)d_ws;       // N*128 bf16
    unsigned short* H  = X + (size_t)N * DIM;         // N*128 bf16
    unsigned short* G  = H + (size_t)N * DIM;         // N*128 bf16
    unsigned short* Wp = G + (size_t)N * DIM;         // 3*32768 bf16
    int2*  perm2 = (int2*)(Wp + 3 * 32768);           // E int2 (8B aligned)
    int*   rowst = (int*)(perm2 + E);                 // N+1 i32
    int*   cursor = rowst + (N + 1);                  // N i32
    int*   counts = cursor + N;                       // N i32

    // CSR build
    zero_ints<<<(3 * N + 1 + 255) / 256, 256, 0, stream>>>(rowst, 3 * N + 1);
    hist_kernel<<<(E + 255) / 256, 256, 0, stream>>>(dstI, counts, E);
    scan_kernel<<<1, 1024, 0, stream>>>(counts, rowst, N);
    fill_kernel<<<(E + 255) / 256, 256, 0, stream>>>(srcI, dstI, ea, rowst, cursor, perm2, E);
    pack_w_bf16<<<(3 * 32768 + 255) / 256, 256, 0, stream>>>(wr0, wt0, wr1, wt1, wr2, wt2, Wp);
    cvt_f2b<<<((N * DIM) + 255) / 256, 256, 0, stream>>>(x, X, N * DIM);

    const int aggGrid  = (N + 3) / 4;            // 4 waves/block, 1 wave/node
    const int gemmGrid = (N + 127) / 128;        // 128 rows/block

    // layer 0
    aggregate_bf16<<<aggGrid, 256, 0, stream>>>(X, rowst, perm2, G, N);
    gemm_mfma<<<gemmGrid, 256, 0, stream>>>(G, X, Wp, br0, nullptr, H, N, 1);
    // layer 1 (in-place H: each block reads only the rows it writes)
    aggregate_bf16<<<aggGrid, 256, 0, stream>>>(H, rowst, perm2, G, N);
    gemm_mfma<<<gemmGrid, 256, 0, stream>>>(G, H, Wp + 32768, br1, nullptr, H, N, 1);
    // layer 2 -> fp32 out
    aggregate_bf16<<<aggGrid, 256, 0, stream>>>(H, rowst, perm2, G, N);
    gemm_mfma<<<gemmGrid, 256, 0, stream>>>(G, H, Wp + 65536, br2, out, nullptr, N, 0);
}